// Round 2
// baseline (291.356 us; speedup 1.0000x reference)
//
#include <hip/hip_runtime.h>
#include <hip/hip_bf16.h>
#include <cstdint>

#define B_N 64
#define C_N 2048
#define HW_N 196
#define HWP 224          // zero-padded hw length for A (7 k-steps of 32)
#define M_N 32
#define NC_N 396
#define K_N 65536        // M_N * C_N
#define CCH 256          // c-chunk per k1a block
#define NCH 8            // number of c-chunks
#define ZSTRIDE (B_N * M_N * HW_N)   // 401408 floats per chunk-partial

typedef __attribute__((ext_vector_type(8))) short bf16x8;
typedef __attribute__((ext_vector_type(4))) float f32x4;

__device__ inline short f2bf(float x) {   // RNE fp32 -> bf16
  union { float f; unsigned u; } v; v.f = x;
  unsigned r = (v.u + 0x7FFFu + ((v.u >> 16) & 1u)) >> 16;
  return (short)r;
}

__device__ inline unsigned packbf2(float lo, float hi) {  // lo -> low 16 bits
  return ((unsigned)(unsigned short)f2bf(hi) << 16) |
         (unsigned)(unsigned short)f2bf(lo);
}

// ---------------------------------------------------------------------------
// K1a: z[cx][b][m][hw] = sum_{c in chunk cx} x[b][c][hw] * Wa[m][c]
// grid(8,64), block 256 (4 waves). Each block owns a 256-c chunk of one b and
// ALL 196 hw -> its global reads are one fully contiguous 200KB region of x,
// loaded as coalesced float4 (1KB/instruction) and transposed into LDS as
// bf16 (paired-c ds_write_b32, 2-way banks = free). MFMA 16x16x32:
// A = Wa[m][c] from LDS (staged once/block), B = xT[hw][c] ds_read_b128
// (80B row stride, 2-way banks = free). hw-tiles 0..12 split across waves.
// ---------------------------------------------------------------------------
__global__ __launch_bounds__(256) void k1a_partial(
    const float* __restrict__ x, const float* __restrict__ Wa,
    float* __restrict__ z) {
  __shared__ short waT[32][264];   // Wa chunk bf16, row stride 528B (pad +8)
  __shared__ short xT[208][40];    // x^T stage [hw][c'] bf16, row stride 80B
  const int t = threadIdx.x;
  const int w = t >> 6, lane = t & 63, lq = lane >> 4, ln = lane & 15;
  const int cx = blockIdx.x, b = blockIdx.y;
  const int c0 = cx * CCH;

  unsigned* xTw = (unsigned*)xT;
  // zero hw rows 196..207 once (read by tile 12, masked on store)
  if (t < 240) xTw[196 * 20 + t] = 0u;
  // stage Wa[0:32][c0:c0+256] -> waT (bf16), coalesced row-major reads
  for (int i = t; i < 2048; i += 256) {
    int m = i >> 6, f4 = i & 63;
    float4 v = *(const float4*)(Wa + (size_t)m * C_N + c0 + f4 * 4);
    uint2 pk;
    pk.x = packbf2(v.x, v.y);
    pk.y = packbf2(v.z, v.w);
    *(uint2*)((char*)waT + m * 528 + f4 * 8) = pk;
  }

  f32x4 acc[4][2];
#pragma unroll
  for (int ti = 0; ti < 4; ++ti) {
    acc[ti][0] = (f32x4){0.f, 0.f, 0.f, 0.f};
    acc[ti][1] = (f32x4){0.f, 0.f, 0.f, 0.f};
  }

  const float* __restrict__ xb0 = x + (size_t)b * (C_N * HW_N) + (size_t)c0 * HW_N;
  const int p0 = t & 15;           // c-pair 0..15
  const int q0 = t >> 4;           // hw-quad 0..15 (then +16, +32, tail 48)

  for (int ss = 0; ss < 8; ++ss) {
    // ---- stage x[b][c0+32ss .. +32][0:196] -> xT (transposed bf16) ----
    const float* xs = xb0 + (size_t)ss * 32 * HW_N;
    {
      const float* r0 = xs + (2 * p0) * HW_N + 4 * q0;
      // issue all 6 main loads first (latency batching)
      float4 fa0 = *(const float4*)r0;
      float4 fb0 = *(const float4*)(r0 + HW_N);
      float4 fa1 = *(const float4*)(r0 + 64);
      float4 fb1 = *(const float4*)(r0 + 64 + HW_N);
      float4 fa2 = *(const float4*)(r0 + 128);
      float4 fb2 = *(const float4*)(r0 + 128 + HW_N);
      unsigned* d0 = xTw + q0 * 80 + p0;          // row 4*q0, col-pair p0
      d0[0]  = packbf2(fa0.x, fb0.x);
      d0[20] = packbf2(fa0.y, fb0.y);
      d0[40] = packbf2(fa0.z, fb0.z);
      d0[60] = packbf2(fa0.w, fb0.w);
      unsigned* d1 = d0 + 1280;                   // q0+16
      d1[0]  = packbf2(fa1.x, fb1.x);
      d1[20] = packbf2(fa1.y, fb1.y);
      d1[40] = packbf2(fa1.z, fb1.z);
      d1[60] = packbf2(fa1.w, fb1.w);
      unsigned* d2 = d0 + 2560;                   // q0+32
      d2[0]  = packbf2(fa2.x, fb2.x);
      d2[20] = packbf2(fa2.y, fb2.y);
      d2[40] = packbf2(fa2.z, fb2.z);
      d2[60] = packbf2(fa2.w, fb2.w);
      if (t < 16) {                               // tail: q=48, hw 192..195
        const float* r3 = xs + (2 * t) * HW_N + 192;
        float4 fa3 = *(const float4*)r3;
        float4 fb3 = *(const float4*)(r3 + HW_N);
        unsigned* d3 = xTw + 48 * 80 + t;
        d3[0]  = packbf2(fa3.x, fb3.x);
        d3[20] = packbf2(fa3.y, fb3.y);
        d3[40] = packbf2(fa3.z, fb3.z);
        d3[60] = packbf2(fa3.w, fb3.w);
      }
    }
    __syncthreads();
    // ---- compute: one K=32 MFMA step over this stage's 32 c ----
    const int kb = ss * 64 + lq * 16;   // byte offset into waT row
    bf16x8 af0 = *(const bf16x8*)((const char*)waT + ln * 528 + kb);
    bf16x8 af1 = *(const bf16x8*)((const char*)waT + (16 + ln) * 528 + kb);
#pragma unroll
    for (int ti = 0; ti < 4; ++ti) {
      int ht = w + ti * 4;
      if (ht < 13) {
        bf16x8 bfr = *(const bf16x8*)((const char*)xT + (ht * 16 + ln) * 80 + lq * 16);
        acc[ti][0] = __builtin_amdgcn_mfma_f32_16x16x32_bf16(af0, bfr, acc[ti][0], 0, 0, 0);
        acc[ti][1] = __builtin_amdgcn_mfma_f32_16x16x32_bf16(af1, bfr, acc[ti][1], 0, 0, 0);
      }
    }
    __syncthreads();
  }

  // ---- store fp32 partials: z[cx][b][m][hw], hw stride 196 ----
  float* zc = z + (size_t)(cx * B_N + b) * (M_N * HW_N);
#pragma unroll
  for (int ti = 0; ti < 4; ++ti) {
    int ht = w + ti * 4;
    if (ht < 13) {
      int hw = ht * 16 + ln;
      if (hw < HW_N) {
#pragma unroll
        for (int mt = 0; mt < 2; ++mt) {
#pragma unroll
          for (int r = 0; r < 4; ++r) {
            int m = mt * 16 + lq * 4 + r;      // C-layout: row = quad*4 + reg
            zc[(size_t)m * HW_N + hw] = acc[ti][mt][r];
          }
        }
      }
    }
  }
}

// ---------------------------------------------------------------------------
// K1b: Apad[b][m][hwp] = sigmoid(ba[m] + sum_cx z[cx][b][m][hw]), 0 for pad.
// grid(1792), block 256 — pure streaming reduce (13.8MB, ~3us).
// ---------------------------------------------------------------------------
__global__ __launch_bounds__(256) void k1b_sig(
    const float* __restrict__ z, const float* __restrict__ ba,
    short* __restrict__ Apad) {
  int idx = blockIdx.x * 256 + threadIdx.x;      // 64*32*224 = 458752
  int b = idx / (M_N * HWP);
  int r = idx - b * (M_N * HWP);
  int m = r / HWP;
  int hw = r - m * HWP;
  short out = 0;
  if (hw < HW_N) {
    float s = ba[m];
    size_t base = ((size_t)b * M_N + m) * HW_N + hw;
#pragma unroll
    for (int cx = 0; cx < NCH; ++cx)
      s += z[(size_t)cx * ZSTRIDE + base];
    out = f2bf(1.f / (1.f + __expf(-s)));
  }
  Apad[idx] = out;
}

// ---------------------------------------------------------------------------
// K2: featsb[b][m*2048+c] = bf16( (1/196) sum_hw x[b][c][hw]*A[b][m][hw] )
// grid(32,64), block 256. k=hw (7 steps of 32, Apad zero-padded).
// A-frags: raw bf16 loads from Apad (no cvt); B-frags: x row-major dwordx4.
// No LDS, no barriers. Tail step predicated (x ends page-exact).
// ---------------------------------------------------------------------------
__global__ __launch_bounds__(256) void k2_bap(
    const float* __restrict__ x, const short* __restrict__ Apad,
    short* __restrict__ featsb) {
  const int t = threadIdx.x;
  const int w = t >> 6, lane = t & 63, lq = lane >> 4, ln = lane & 15;
  const int b = blockIdx.y;
  const int c = blockIdx.x * 64 + w * 16 + ln;
  const float* __restrict__ xrow = x + (size_t)b * (C_N * HW_N) + (size_t)c * HW_N;
  const short* __restrict__ ap0 = Apad + ((size_t)b * M_N + ln) * HWP + lq * 8;
  const short* __restrict__ ap1 = ap0 + 16 * HWP;

  f32x4 d0 = {0.f, 0.f, 0.f, 0.f}, d1 = {0.f, 0.f, 0.f, 0.f};
#pragma unroll
  for (int s = 0; s < 7; ++s) {
    bf16x8 a0 = *(const bf16x8*)(ap0 + s * 32);
    bf16x8 a1 = *(const bf16x8*)(ap1 + s * 32);
    bf16x8 bfr;
    const int h = s * 32 + lq * 8;
    if (s < 6) {
      float4 b0 = *(const float4*)(xrow + h);
      float4 b1 = *(const float4*)(xrow + h + 4);
      bfr[0]=f2bf(b0.x); bfr[1]=f2bf(b0.y); bfr[2]=f2bf(b0.z); bfr[3]=f2bf(b0.w);
      bfr[4]=f2bf(b1.x); bfr[5]=f2bf(b1.y); bfr[6]=f2bf(b1.z); bfr[7]=f2bf(b1.w);
    } else {
      // hw 192..223: only quad 0 j0..3 (hw 192..195) exists; rest hit A=0 pad
      float4 b0 = make_float4(0.f, 0.f, 0.f, 0.f);
      if (lq == 0) b0 = *(const float4*)(xrow + h);
      bfr[0]=f2bf(b0.x); bfr[1]=f2bf(b0.y); bfr[2]=f2bf(b0.z); bfr[3]=f2bf(b0.w);
      bfr[4]=0; bfr[5]=0; bfr[6]=0; bfr[7]=0;
    }
    d0 = __builtin_amdgcn_mfma_f32_16x16x32_bf16(a0, bfr, d0, 0, 0, 0);
    d1 = __builtin_amdgcn_mfma_f32_16x16x32_bf16(a1, bfr, d1, 0, 0, 0);
  }
  const float sc = 1.f / (float)HW_N;
  short* fb = featsb + (size_t)b * K_N + c;
#pragma unroll
  for (int r = 0; r < 4; ++r) {
    int m0 = lq * 4 + r;
    fb[(size_t)m0 * C_N]        = f2bf(d0[r] * sc);
    fb[(size_t)(16 + m0) * C_N] = f2bf(d1[r] * sc);
  }
}

// ---------------------------------------------------------------------------
// K3: partial[kc][b][n] = sum_{k in chunk} feats[b][k] * Wc[n][k]
// grid(7,128), block 256, k-chunk 512. Wc panel [64n][512k] is staged
// through LDS: coalesced float4 global reads (one contiguous 2KB row segment
// per wave-iteration), packed to bf16, stored with 16B-chunk XOR swizzle
// (chunk ^= row&7) so the B-frag ds_read_b128 (row stride 1024B) is 2-way
// bank-aliased = free. feats A-frags stay direct-global (8.4MB, L2/L3-hot;
// consecutive blocks share the same feats k-chunk).
// ---------------------------------------------------------------------------
__global__ __launch_bounds__(256) void k3_cls(
    const short* __restrict__ featsb, const float* __restrict__ Wc,
    float* __restrict__ partial) {
  __shared__ short wls[64][512];    // 64KB bf16, XOR-swizzled 16B chunks
  const int t = threadIdx.x;
  const int w = t >> 6, lane = t & 63, lq = lane >> 4, ln = lane & 15;
  const int n0 = blockIdx.x * 64;
  const int n = n0 + w * 16 + ln;
  const size_t k0 = (size_t)blockIdx.y * 512;

  // ---- stage Wc[n0:n0+64][k0:k0+512] -> LDS bf16 ----
#pragma unroll 4
  for (int i = 0; i < 16; ++i) {
    int g = i * 256 + t;            // 0..4095
    int r = g >> 6, c = g & 63;     // row (n-offset), 16B chunk (8 floats)
    int nr = n0 + r; if (nr >= NC_N) nr = NC_N - 1;
    const float* src = Wc + (size_t)nr * K_N + k0 + c * 8;
    float4 v0 = *(const float4*)src;
    float4 v1 = *(const float4*)(src + 4);
    uint4 pk;
    pk.x = packbf2(v0.x, v0.y); pk.y = packbf2(v0.z, v0.w);
    pk.z = packbf2(v1.x, v1.y); pk.w = packbf2(v1.z, v1.w);
    int cs = c ^ (r & 7);
    *(uint4*)((char*)wls + r * 1024 + cs * 16) = pk;
  }
  __syncthreads();

  const short* __restrict__ f0 = featsb + k0 + lq * 8 + (size_t)ln * K_N;
  const int brow = w * 16 + ln;     // this lane's Wc row in LDS

  f32x4 acc0 = {0.f,0.f,0.f,0.f}, acc1 = {0.f,0.f,0.f,0.f};
  f32x4 acc2 = {0.f,0.f,0.f,0.f}, acc3 = {0.f,0.f,0.f,0.f};
#pragma unroll 4
  for (int s = 0; s < 16; ++s) {
    const int kk = s * 32;
    int cs = (s * 4 + lq) ^ (brow & 7);
    bf16x8 bfr = *(const bf16x8*)((const char*)wls + brow * 1024 + cs * 16);
    bf16x8 a0 = *(const bf16x8*)(f0 + kk);
    bf16x8 a1 = *(const bf16x8*)(f0 + (size_t)16 * K_N + kk);
    bf16x8 a2 = *(const bf16x8*)(f0 + (size_t)32 * K_N + kk);
    bf16x8 a3 = *(const bf16x8*)(f0 + (size_t)48 * K_N + kk);
    acc0 = __builtin_amdgcn_mfma_f32_16x16x32_bf16(a0, bfr, acc0, 0, 0, 0);
    acc1 = __builtin_amdgcn_mfma_f32_16x16x32_bf16(a1, bfr, acc1, 0, 0, 0);
    acc2 = __builtin_amdgcn_mfma_f32_16x16x32_bf16(a2, bfr, acc2, 0, 0, 0);
    acc3 = __builtin_amdgcn_mfma_f32_16x16x32_bf16(a3, bfr, acc3, 0, 0, 0);
  }
  if (n < NC_N) {
    float* po = partial + (size_t)blockIdx.y * (B_N * NC_N) + n;
#pragma unroll
    for (int r = 0; r < 4; ++r) {
      int br = lq * 4 + r;                    // b within 16-tile
      po[(size_t)br * NC_N]        = acc0[r];
      po[(size_t)(16 + br) * NC_N] = acc1[r];
      po[(size_t)(32 + br) * NC_N] = acc2[r];
      po[(size_t)(48 + br) * NC_N] = acc3[r];
    }
  }
}

// ---------------------------------------------------------------------------
// K4: out[b][n] = bc[n] + sum_kc partial[kc][b][n]   (128 chunks)
// ---------------------------------------------------------------------------
__global__ __launch_bounds__(256) void k4_reduce(
    const float* __restrict__ partial, const float* __restrict__ bc,
    float* __restrict__ out) {
  int idx = blockIdx.x * 256 + threadIdx.x;  // 25344 total
  if (idx >= B_N * NC_N) return;
  int n = idx % NC_N;
  float s = bc[n];
#pragma unroll 8
  for (int kc = 0; kc < 128; ++kc) s += partial[(size_t)kc * (B_N * NC_N) + idx];
  out[idx] = s;
}

// ---------------------------------------------------------------------------
extern "C" void kernel_launch(void* const* d_in, const int* in_sizes, int n_in,
                              void* d_out, int out_size, void* d_ws, size_t ws_size,
                              hipStream_t stream) {
  const float* x  = (const float*)d_in[0];
  const float* Wa = (const float*)d_in[1];
  const float* ba = (const float*)d_in[2];
  const float* Wc = (const float*)d_in[3];
  const float* bc = (const float*)d_in[4];
  float* out = (float*)d_out;

  char* wsb = (char*)d_ws;
  short* Apad    = (short*)(wsb);                // 64*32*224*2   = 0.92 MB
  short* featsb  = (short*)(wsb + (1u  << 20));  // 64*65536*2    = 8.39 MB
  float* partial = (float*)(wsb + (10u << 20));  // 128*25344*4   = 12.98 MB
  // zbuf aliases partial: 8*401408*4 = 12.85 MB < 12.98 MB; consumed by k1b
  // before k3 writes partial over it.
  float* zbuf    = (float*)(wsb + (10u << 20));
  (void)ws_size; (void)in_sizes; (void)n_in; (void)out_size;

  hipLaunchKernelGGL(k1a_partial, dim3(NCH, B_N), dim3(256), 0, stream,
                     x, Wa, zbuf);
  hipLaunchKernelGGL(k1b_sig, dim3(1792), dim3(256), 0, stream,
                     zbuf, ba, Apad);
  hipLaunchKernelGGL(k2_bap, dim3(32, 64), dim3(256), 0, stream,
                     x, Apad, featsb);
  hipLaunchKernelGGL(k3_cls, dim3(7, 128), dim3(256), 0, stream,
                     featsb, Wc, partial);
  hipLaunchKernelGGL(k4_reduce, dim3(99), dim3(256), 0, stream,
                     partial, bc, out);
}

// Round 3
// 279.398 us; speedup vs baseline: 1.0428x; 1.0428x over previous
//
#include <hip/hip_runtime.h>
#include <hip/hip_bf16.h>
#include <cstdint>

#define B_N 64
#define C_N 2048
#define HW_N 196
#define HWP 224          // zero-padded hw length for A (7 k-steps of 32)
#define M_N 32
#define NC_N 396
#define K_N 65536        // M_N * C_N
#define CCH 256          // c-chunk per k1a block
#define NCH 8            // number of c-chunks
#define ZSTRIDE (B_N * M_N * HW_N)   // 401408 floats per chunk-partial

typedef __attribute__((ext_vector_type(8))) short bf16x8;
typedef __attribute__((ext_vector_type(4))) float f32x4;

__device__ inline short f2bf(float x) {   // RNE fp32 -> bf16
  union { float f; unsigned u; } v; v.f = x;
  unsigned r = (v.u + 0x7FFFu + ((v.u >> 16) & 1u)) >> 16;
  return (short)r;
}

__device__ inline unsigned packbf2(float lo, float hi) {  // lo -> low 16 bits
  return ((unsigned)(unsigned short)f2bf(hi) << 16) |
         (unsigned)(unsigned short)f2bf(lo);
}

// ---------------------------------------------------------------------------
// K1a: z[cx][b][m][hw] = sum_{c in chunk cx} x[b][c][hw] * Wa[m][c]
// grid(8,64), block 256 (4 waves). Each block owns a 256-c chunk of one b and
// ALL 196 hw -> its global reads are one fully contiguous 200KB region of x,
// loaded as coalesced float4 (1KB/instruction) and transposed into LDS as
// bf16 (paired-c ds_write_b32, 2-way banks = free). MFMA 16x16x32:
// A = Wa[m][c] from LDS (staged once/block), B = xT[hw][c] ds_read_b128
// (80B row stride, 2-way banks = free). hw-tiles 0..12 split across waves.
// ---------------------------------------------------------------------------
__global__ __launch_bounds__(256) void k1a_partial(
    const float* __restrict__ x, const float* __restrict__ Wa,
    float* __restrict__ z) {
  __shared__ short waT[32][264];   // Wa chunk bf16, row stride 528B (pad +8)
  __shared__ short xT[208][40];    // x^T stage [hw][c'] bf16, row stride 80B
  const int t = threadIdx.x;
  const int w = t >> 6, lane = t & 63, lq = lane >> 4, ln = lane & 15;
  const int cx = blockIdx.x, b = blockIdx.y;
  const int c0 = cx * CCH;

  unsigned* xTw = (unsigned*)xT;
  // zero hw rows 196..207 once (read by tile 12, masked on store)
  if (t < 240) xTw[196 * 20 + t] = 0u;
  // stage Wa[0:32][c0:c0+256] -> waT (bf16), coalesced row-major reads
  for (int i = t; i < 2048; i += 256) {
    int m = i >> 6, f4 = i & 63;
    float4 v = *(const float4*)(Wa + (size_t)m * C_N + c0 + f4 * 4);
    uint2 pk;
    pk.x = packbf2(v.x, v.y);
    pk.y = packbf2(v.z, v.w);
    *(uint2*)((char*)waT + m * 528 + f4 * 8) = pk;
  }

  f32x4 acc[4][2];
#pragma unroll
  for (int ti = 0; ti < 4; ++ti) {
    acc[ti][0] = (f32x4){0.f, 0.f, 0.f, 0.f};
    acc[ti][1] = (f32x4){0.f, 0.f, 0.f, 0.f};
  }

  const float* __restrict__ xb0 = x + (size_t)b * (C_N * HW_N) + (size_t)c0 * HW_N;
  const int p0 = t & 15;           // c-pair 0..15
  const int q0 = t >> 4;           // hw-quad 0..15 (then +16, +32, tail 48)

  for (int ss = 0; ss < 8; ++ss) {
    // ---- stage x[b][c0+32ss .. +32][0:196] -> xT (transposed bf16) ----
    const float* xs = xb0 + (size_t)ss * 32 * HW_N;
    {
      const float* r0 = xs + (2 * p0) * HW_N + 4 * q0;
      // issue all 6 main loads first (latency batching)
      float4 fa0 = *(const float4*)r0;
      float4 fb0 = *(const float4*)(r0 + HW_N);
      float4 fa1 = *(const float4*)(r0 + 64);
      float4 fb1 = *(const float4*)(r0 + 64 + HW_N);
      float4 fa2 = *(const float4*)(r0 + 128);
      float4 fb2 = *(const float4*)(r0 + 128 + HW_N);
      unsigned* d0 = xTw + q0 * 80 + p0;          // row 4*q0, col-pair p0
      d0[0]  = packbf2(fa0.x, fb0.x);
      d0[20] = packbf2(fa0.y, fb0.y);
      d0[40] = packbf2(fa0.z, fb0.z);
      d0[60] = packbf2(fa0.w, fb0.w);
      unsigned* d1 = d0 + 1280;                   // q0+16
      d1[0]  = packbf2(fa1.x, fb1.x);
      d1[20] = packbf2(fa1.y, fb1.y);
      d1[40] = packbf2(fa1.z, fb1.z);
      d1[60] = packbf2(fa1.w, fb1.w);
      unsigned* d2 = d0 + 2560;                   // q0+32
      d2[0]  = packbf2(fa2.x, fb2.x);
      d2[20] = packbf2(fa2.y, fb2.y);
      d2[40] = packbf2(fa2.z, fb2.z);
      d2[60] = packbf2(fa2.w, fb2.w);
      if (t < 16) {                               // tail: q=48, hw 192..195
        const float* r3 = xs + (2 * t) * HW_N + 192;
        float4 fa3 = *(const float4*)r3;
        float4 fb3 = *(const float4*)(r3 + HW_N);
        unsigned* d3 = xTw + 48 * 80 + t;
        d3[0]  = packbf2(fa3.x, fb3.x);
        d3[20] = packbf2(fa3.y, fb3.y);
        d3[40] = packbf2(fa3.z, fb3.z);
        d3[60] = packbf2(fa3.w, fb3.w);
      }
    }
    __syncthreads();
    // ---- compute: one K=32 MFMA step over this stage's 32 c ----
    const int kb = ss * 64 + lq * 16;   // byte offset into waT row
    bf16x8 af0 = *(const bf16x8*)((const char*)waT + ln * 528 + kb);
    bf16x8 af1 = *(const bf16x8*)((const char*)waT + (16 + ln) * 528 + kb);
#pragma unroll
    for (int ti = 0; ti < 4; ++ti) {
      int ht = w + ti * 4;
      if (ht < 13) {
        bf16x8 bfr = *(const bf16x8*)((const char*)xT + (ht * 16 + ln) * 80 + lq * 16);
        acc[ti][0] = __builtin_amdgcn_mfma_f32_16x16x32_bf16(af0, bfr, acc[ti][0], 0, 0, 0);
        acc[ti][1] = __builtin_amdgcn_mfma_f32_16x16x32_bf16(af1, bfr, acc[ti][1], 0, 0, 0);
      }
    }
    __syncthreads();
  }

  // ---- store fp32 partials: z[cx][b][m][hw], hw stride 196 ----
  float* zc = z + (size_t)(cx * B_N + b) * (M_N * HW_N);
#pragma unroll
  for (int ti = 0; ti < 4; ++ti) {
    int ht = w + ti * 4;
    if (ht < 13) {
      int hw = ht * 16 + ln;
      if (hw < HW_N) {
#pragma unroll
        for (int mt = 0; mt < 2; ++mt) {
#pragma unroll
          for (int r = 0; r < 4; ++r) {
            int m = mt * 16 + lq * 4 + r;      // C-layout: row = quad*4 + reg
            zc[(size_t)m * HW_N + hw] = acc[ti][mt][r];
          }
        }
      }
    }
  }
}

// ---------------------------------------------------------------------------
// K1b: Apad[b][m][hwp] = sigmoid(ba[m] + sum_cx z[cx][b][m][hw]), 0 for pad.
// grid(1792), block 256 — pure streaming reduce (13.8MB, ~3us).
// ---------------------------------------------------------------------------
__global__ __launch_bounds__(256) void k1b_sig(
    const float* __restrict__ z, const float* __restrict__ ba,
    short* __restrict__ Apad) {
  int idx = blockIdx.x * 256 + threadIdx.x;      // 64*32*224 = 458752
  int b = idx / (M_N * HWP);
  int r = idx - b * (M_N * HWP);
  int m = r / HWP;
  int hw = r - m * HWP;
  short out = 0;
  if (hw < HW_N) {
    float s = ba[m];
    size_t base = ((size_t)b * M_N + m) * HW_N + hw;
#pragma unroll
    for (int cx = 0; cx < NCH; ++cx)
      s += z[(size_t)cx * ZSTRIDE + base];
    out = f2bf(1.f / (1.f + __expf(-s)));
  }
  Apad[idx] = out;
}

// ---------------------------------------------------------------------------
// K2: BAP -> featsb, written in MFMA-FRAGMENT layout for k3:
//   value (b, m, c) with k = m*2048+c lives at
//   off = ((sg*4 + bt)*64 + lq2*16 + (b&15))*8 + (c&7), sg = k>>5 = m*64+(c>>5),
//   bt = b>>4, lq2 = (c>>3)&3.  Same byte count as before (scattered scalar
//   shorts either way); makes k3's A-loads fully coalesced 1KB wave loads.
// grid(32,64), block 256. k=hw (7 steps of 32, Apad zero-padded).
// ---------------------------------------------------------------------------
__global__ __launch_bounds__(256) void k2_bap(
    const float* __restrict__ x, const short* __restrict__ Apad,
    short* __restrict__ featsb) {
  const int t = threadIdx.x;
  const int w = t >> 6, lane = t & 63, lq = lane >> 4, ln = lane & 15;
  const int b = blockIdx.y;
  const int c = blockIdx.x * 64 + w * 16 + ln;
  const float* __restrict__ xrow = x + (size_t)b * (C_N * HW_N) + (size_t)c * HW_N;
  const short* __restrict__ ap0 = Apad + ((size_t)b * M_N + ln) * HWP + lq * 8;
  const short* __restrict__ ap1 = ap0 + 16 * HWP;

  f32x4 d0 = {0.f, 0.f, 0.f, 0.f}, d1 = {0.f, 0.f, 0.f, 0.f};
#pragma unroll
  for (int s = 0; s < 7; ++s) {
    bf16x8 a0 = *(const bf16x8*)(ap0 + s * 32);
    bf16x8 a1 = *(const bf16x8*)(ap1 + s * 32);
    bf16x8 bfr;
    const int h = s * 32 + lq * 8;
    if (s < 6) {
      float4 b0 = *(const float4*)(xrow + h);
      float4 b1 = *(const float4*)(xrow + h + 4);
      bfr[0]=f2bf(b0.x); bfr[1]=f2bf(b0.y); bfr[2]=f2bf(b0.z); bfr[3]=f2bf(b0.w);
      bfr[4]=f2bf(b1.x); bfr[5]=f2bf(b1.y); bfr[6]=f2bf(b1.z); bfr[7]=f2bf(b1.w);
    } else {
      // hw 192..223: only quad 0 j0..3 (hw 192..195) exists; rest hit A=0 pad
      float4 b0 = make_float4(0.f, 0.f, 0.f, 0.f);
      if (lq == 0) b0 = *(const float4*)(xrow + h);
      bfr[0]=f2bf(b0.x); bfr[1]=f2bf(b0.y); bfr[2]=f2bf(b0.z); bfr[3]=f2bf(b0.w);
      bfr[4]=0; bfr[5]=0; bfr[6]=0; bfr[7]=0;
    }
    d0 = __builtin_amdgcn_mfma_f32_16x16x32_bf16(a0, bfr, d0, 0, 0, 0);
    d1 = __builtin_amdgcn_mfma_f32_16x16x32_bf16(a1, bfr, d1, 0, 0, 0);
  }
  const float sc = 1.f / (float)HW_N;
  // fragment-layout store base for this thread's (b, c)
  const int bt = b >> 4, bl = b & 15;
  const int lq2 = (c >> 3) & 3, j = c & 7;
  const int cs5 = c >> 5;
  short* fb = featsb + ((size_t)bt * 64 + (size_t)lq2 * 16 + bl) * 8 + j;
#pragma unroll
  for (int r = 0; r < 4; ++r) {
    int m0 = lq * 4 + r;                    // C-layout: row = quad*4 + reg
    fb[(size_t)(m0 * 64 + cs5) * 2048]        = f2bf(d0[r] * sc);
    fb[(size_t)((16 + m0) * 64 + cs5) * 2048] = f2bf(d1[r] * sc);
  }
}

// ---------------------------------------------------------------------------
// K3: partial[kc][b][n] = sum_{k in chunk} feats[b][k] * Wc[n][k]
// grid(7,128), block 256, k-chunk 512. No LDS, no barriers.
// A-frags: COALESCED 1KB wave loads from fragment-layout featsb.
// B-frags: direct Wc float4 pairs (16 rows x 128B per iter, full lines).
// Explicit 1-deep software prefetch keeps ~12 loads/wave in flight so the
// loop is BW-bound, not latency-bound (old VGPR=56 schedule had ~1 iter MLP).
// ---------------------------------------------------------------------------
__global__ __launch_bounds__(256) void k3_cls(
    const short* __restrict__ featsb, const float* __restrict__ Wc,
    float* __restrict__ partial) {
  const int t = threadIdx.x;
  const int w = t >> 6, lane = t & 63, lq = lane >> 4, ln = lane & 15;
  const int n = blockIdx.x * 64 + w * 16 + ln;
  const int nc = n < NC_N ? n : NC_N - 1;
  const int kc = blockIdx.y;
  const size_t k0 = (size_t)kc * 512;
  const float* __restrict__ wrow = Wc + (size_t)nc * K_N + k0 + lq * 8;
  // fragment base: steps sg = kc*16 + s; per-step stride 2048 shorts,
  // per-b-tile stride 512 shorts, per-lane 8 shorts (16B, coalesced).
  const short* __restrict__ fb = featsb + (size_t)(kc * 16) * 2048 + lane * 8;

  f32x4 acc0 = {0.f,0.f,0.f,0.f}, acc1 = {0.f,0.f,0.f,0.f};
  f32x4 acc2 = {0.f,0.f,0.f,0.f}, acc3 = {0.f,0.f,0.f,0.f};

  float4 cw0 = *(const float4*)(wrow);
  float4 cw1 = *(const float4*)(wrow + 4);
  bf16x8 ca0 = *(const bf16x8*)(fb);
  bf16x8 ca1 = *(const bf16x8*)(fb + 512);
  bf16x8 ca2 = *(const bf16x8*)(fb + 1024);
  bf16x8 ca3 = *(const bf16x8*)(fb + 1536);

#pragma unroll
  for (int s = 0; s < 16; ++s) {
    float4 nw0, nw1; bf16x8 na0, na1, na2, na3;
    if (s < 15) {                    // prefetch step s+1 before MFMAs of s
      const float* wn = wrow + (s + 1) * 32;
      nw0 = *(const float4*)(wn);
      nw1 = *(const float4*)(wn + 4);
      const short* fs = fb + (size_t)(s + 1) * 2048;
      na0 = *(const bf16x8*)(fs);
      na1 = *(const bf16x8*)(fs + 512);
      na2 = *(const bf16x8*)(fs + 1024);
      na3 = *(const bf16x8*)(fs + 1536);
    }
    bf16x8 bfr;
    bfr[0]=f2bf(cw0.x); bfr[1]=f2bf(cw0.y); bfr[2]=f2bf(cw0.z); bfr[3]=f2bf(cw0.w);
    bfr[4]=f2bf(cw1.x); bfr[5]=f2bf(cw1.y); bfr[6]=f2bf(cw1.z); bfr[7]=f2bf(cw1.w);
    acc0 = __builtin_amdgcn_mfma_f32_16x16x32_bf16(ca0, bfr, acc0, 0, 0, 0);
    acc1 = __builtin_amdgcn_mfma_f32_16x16x32_bf16(ca1, bfr, acc1, 0, 0, 0);
    acc2 = __builtin_amdgcn_mfma_f32_16x16x32_bf16(ca2, bfr, acc2, 0, 0, 0);
    acc3 = __builtin_amdgcn_mfma_f32_16x16x32_bf16(ca3, bfr, acc3, 0, 0, 0);
    if (s < 15) {
      cw0 = nw0; cw1 = nw1;
      ca0 = na0; ca1 = na1; ca2 = na2; ca3 = na3;
    }
  }
  if (n < NC_N) {
    float* po = partial + (size_t)blockIdx.y * (B_N * NC_N) + n;
#pragma unroll
    for (int r = 0; r < 4; ++r) {
      int br = lq * 4 + r;                    // b within 16-tile
      po[(size_t)br * NC_N]        = acc0[r];
      po[(size_t)(16 + br) * NC_N] = acc1[r];
      po[(size_t)(32 + br) * NC_N] = acc2[r];
      po[(size_t)(48 + br) * NC_N] = acc3[r];
    }
  }
}

// ---------------------------------------------------------------------------
// K4: out[b][n] = bc[n] + sum_kc partial[kc][b][n]   (128 chunks)
// ---------------------------------------------------------------------------
__global__ __launch_bounds__(256) void k4_reduce(
    const float* __restrict__ partial, const float* __restrict__ bc,
    float* __restrict__ out) {
  int idx = blockIdx.x * 256 + threadIdx.x;  // 25344 total
  if (idx >= B_N * NC_N) return;
  int n = idx % NC_N;
  float s = bc[n];
#pragma unroll 8
  for (int kc = 0; kc < 128; ++kc) s += partial[(size_t)kc * (B_N * NC_N) + idx];
  out[idx] = s;
}

// ---------------------------------------------------------------------------
extern "C" void kernel_launch(void* const* d_in, const int* in_sizes, int n_in,
                              void* d_out, int out_size, void* d_ws, size_t ws_size,
                              hipStream_t stream) {
  const float* x  = (const float*)d_in[0];
  const float* Wa = (const float*)d_in[1];
  const float* ba = (const float*)d_in[2];
  const float* Wc = (const float*)d_in[3];
  const float* bc = (const float*)d_in[4];
  float* out = (float*)d_out;

  char* wsb = (char*)d_ws;
  short* Apad    = (short*)(wsb);                // 64*32*224*2   = 0.92 MB
  short* featsb  = (short*)(wsb + (1u  << 20));  // 2048*2048*2   = 8.39 MB (frag layout)
  float* partial = (float*)(wsb + (10u << 20));  // 128*25344*4   = 12.98 MB
  // zbuf aliases partial: 8*401408*4 = 12.85 MB < 12.98 MB; consumed by k1b
  // before k3 writes partial over it.
  float* zbuf    = (float*)(wsb + (10u << 20));
  (void)ws_size; (void)in_sizes; (void)n_in; (void)out_size;

  hipLaunchKernelGGL(k1a_partial, dim3(NCH, B_N), dim3(256), 0, stream,
                     x, Wa, zbuf);
  hipLaunchKernelGGL(k1b_sig, dim3(1792), dim3(256), 0, stream,
                     zbuf, ba, Apad);
  hipLaunchKernelGGL(k2_bap, dim3(32, 64), dim3(256), 0, stream,
                     x, Apad, featsb);
  hipLaunchKernelGGL(k3_cls, dim3(7, 128), dim3(256), 0, stream,
                     featsb, Wc, partial);
  hipLaunchKernelGGL(k4_reduce, dim3(99), dim3(256), 0, stream,
                     partial, bc, out);
}

// Round 5
// 270.494 us; speedup vs baseline: 1.0771x; 1.0329x over previous
//
#include <hip/hip_runtime.h>
#include <hip/hip_bf16.h>
#include <cstdint>

#define B_N 64
#define C_N 2048
#define HW_N 196
#define HWP 224          // zero-padded hw length for A (7 k-steps of 32)
#define M_N 32
#define NC_N 396
#define K_N 65536        // M_N * C_N
#define CCH 256          // c-chunk per k1a block
#define NCH 8            // number of c-chunks
#define KCH 64           // k3 k-chunks (k-chunk = 1024)
#define ZSTRIDE (B_N * M_N * HW_N)   // 401408 floats per chunk-partial

typedef __attribute__((ext_vector_type(8))) short bf16x8;
typedef __attribute__((ext_vector_type(4))) float f32x4;

__device__ inline short f2bf(float x) {   // RNE fp32 -> bf16
  union { float f; unsigned u; } v; v.f = x;
  unsigned r = (v.u + 0x7FFFu + ((v.u >> 16) & 1u)) >> 16;
  return (short)r;
}

__device__ inline unsigned packbf2(float lo, float hi) {  // lo -> low 16 bits
  return ((unsigned)(unsigned short)f2bf(hi) << 16) |
         (unsigned)(unsigned short)f2bf(lo);
}

// ---------------------------------------------------------------------------
// K1a: z[cx][b][m][hw] = sum_{c in chunk cx} x[b][c][hw] * Wa[m][c]
// grid(8,64), block 256 (4 waves). DOUBLE-BUFFERED xT stage: stage ss+1's
// global loads are issued into registers BEFORE stage ss's MFMAs, the
// pack+ds_write lands in the other buffer after them, one barrier per stage.
// HBM latency hides under compute instead of serializing per stage.
// ---------------------------------------------------------------------------
__global__ __launch_bounds__(256) void k1a_partial(
    const float* __restrict__ x, const float* __restrict__ Wa,
    float* __restrict__ z) {
  __shared__ short waT[32][264];      // Wa chunk bf16, row stride 528B (pad +8)
  __shared__ short xT[2][208][40];    // x^T stages [hw][c'] bf16, stride 80B
  const int t = threadIdx.x;
  const int w = t >> 6, lane = t & 63, lq = lane >> 4, ln = lane & 15;
  const int cx = blockIdx.x, b = blockIdx.y;
  const int c0 = cx * CCH;

  unsigned* xTw0 = (unsigned*)xT[0];
  unsigned* xTw1 = (unsigned*)xT[1];
  // zero hw rows 196..207 of both buffers (read by tile 12, masked on store)
  if (t < 240) { xTw0[196 * 20 + t] = 0u; xTw1[196 * 20 + t] = 0u; }
  // stage Wa[0:32][c0:c0+256] -> waT (bf16), coalesced row-major reads
  for (int i = t; i < 2048; i += 256) {
    int m = i >> 6, f4 = i & 63;
    float4 v = *(const float4*)(Wa + (size_t)m * C_N + c0 + f4 * 4);
    uint2 pk;
    pk.x = packbf2(v.x, v.y);
    pk.y = packbf2(v.z, v.w);
    *(uint2*)((char*)waT + m * 528 + f4 * 8) = pk;
  }

  f32x4 acc[4][2];
#pragma unroll
  for (int ti = 0; ti < 4; ++ti) {
    acc[ti][0] = (f32x4){0.f, 0.f, 0.f, 0.f};
    acc[ti][1] = (f32x4){0.f, 0.f, 0.f, 0.f};
  }

  const float* __restrict__ xb0 = x + (size_t)b * (C_N * HW_N) + (size_t)c0 * HW_N;
  const int p0 = t & 15;           // c-pair 0..15
  const int q0 = t >> 4;           // hw-quad 0..15 (then +16, +32, tail 48)

  float4 fa0, fb0, fa1, fb1, fa2, fb2, fa3, fb3;
  auto LD = [&](int ss) {
    const float* xs = xb0 + (size_t)ss * 32 * HW_N;
    const float* r0 = xs + (2 * p0) * HW_N + 4 * q0;
    fa0 = *(const float4*)r0;
    fb0 = *(const float4*)(r0 + HW_N);
    fa1 = *(const float4*)(r0 + 64);
    fb1 = *(const float4*)(r0 + 64 + HW_N);
    fa2 = *(const float4*)(r0 + 128);
    fb2 = *(const float4*)(r0 + 128 + HW_N);
    if (t < 16) {                               // tail: q=48, hw 192..195
      const float* r3 = xs + (2 * t) * HW_N + 192;
      fa3 = *(const float4*)r3;
      fb3 = *(const float4*)(r3 + HW_N);
    }
  };
  auto STORE = [&](unsigned* xw) {
    unsigned* d0 = xw + q0 * 80 + p0;          // row 4*q0, col-pair p0
    d0[0]  = packbf2(fa0.x, fb0.x);
    d0[20] = packbf2(fa0.y, fb0.y);
    d0[40] = packbf2(fa0.z, fb0.z);
    d0[60] = packbf2(fa0.w, fb0.w);
    unsigned* d1 = d0 + 1280;                   // q0+16
    d1[0]  = packbf2(fa1.x, fb1.x);
    d1[20] = packbf2(fa1.y, fb1.y);
    d1[40] = packbf2(fa1.z, fb1.z);
    d1[60] = packbf2(fa1.w, fb1.w);
    unsigned* d2 = d0 + 2560;                   // q0+32
    d2[0]  = packbf2(fa2.x, fb2.x);
    d2[20] = packbf2(fa2.y, fb2.y);
    d2[40] = packbf2(fa2.z, fb2.z);
    d2[60] = packbf2(fa2.w, fb2.w);
    if (t < 16) {
      unsigned* d3 = xw + 48 * 80 + t;
      d3[0]  = packbf2(fa3.x, fb3.x);
      d3[20] = packbf2(fa3.y, fb3.y);
      d3[40] = packbf2(fa3.z, fb3.z);
      d3[60] = packbf2(fa3.w, fb3.w);
    }
  };

  LD(0);
  STORE(xTw0);
  __syncthreads();

  for (int ss = 0; ss < 8; ++ss) {
    if (ss < 7) LD(ss + 1);          // in flight during this stage's MFMAs
    const char* xb = (const char*)xT[ss & 1];
    const int kb = ss * 64 + lq * 16;   // byte offset into waT row
    bf16x8 af0 = *(const bf16x8*)((const char*)waT + ln * 528 + kb);
    bf16x8 af1 = *(const bf16x8*)((const char*)waT + (16 + ln) * 528 + kb);
#pragma unroll
    for (int ti = 0; ti < 4; ++ti) {
      int ht = w + ti * 4;
      if (ht < 13) {
        bf16x8 bfr = *(const bf16x8*)(xb + (ht * 16 + ln) * 80 + lq * 16);
        acc[ti][0] = __builtin_amdgcn_mfma_f32_16x16x32_bf16(af0, bfr, acc[ti][0], 0, 0, 0);
        acc[ti][1] = __builtin_amdgcn_mfma_f32_16x16x32_bf16(af1, bfr, acc[ti][1], 0, 0, 0);
      }
    }
    if (ss < 7) STORE((ss & 1) ? xTw0 : xTw1);  // write OTHER buffer
    __syncthreads();
  }

  // ---- store fp32 partials: z[cx][b][m][hw], hw stride 196 ----
  float* zc = z + (size_t)(cx * B_N + b) * (M_N * HW_N);
#pragma unroll
  for (int ti = 0; ti < 4; ++ti) {
    int ht = w + ti * 4;
    if (ht < 13) {
      int hw = ht * 16 + ln;
      if (hw < HW_N) {
#pragma unroll
        for (int mt = 0; mt < 2; ++mt) {
#pragma unroll
          for (int r = 0; r < 4; ++r) {
            int m = mt * 16 + lq * 4 + r;      // C-layout: row = quad*4 + reg
            zc[(size_t)m * HW_N + hw] = acc[ti][mt][r];
          }
        }
      }
    }
  }
}

// ---------------------------------------------------------------------------
// K1b: Apad[b][m][hwp] = sigmoid(ba[m] + sum_cx z[cx][b][m][hw]), 0 for pad.
// grid(1792), block 256 — pure streaming reduce (13.8MB, ~3us).
// ---------------------------------------------------------------------------
__global__ __launch_bounds__(256) void k1b_sig(
    const float* __restrict__ z, const float* __restrict__ ba,
    short* __restrict__ Apad) {
  int idx = blockIdx.x * 256 + threadIdx.x;      // 64*32*224 = 458752
  int b = idx / (M_N * HWP);
  int r = idx - b * (M_N * HWP);
  int m = r / HWP;
  int hw = r - m * HWP;
  short out = 0;
  if (hw < HW_N) {
    float s = ba[m];
    size_t base = ((size_t)b * M_N + m) * HW_N + hw;
#pragma unroll
    for (int cx = 0; cx < NCH; ++cx)
      s += z[(size_t)cx * ZSTRIDE + base];
    out = f2bf(1.f / (1.f + __expf(-s)));
  }
  Apad[idx] = out;
}

// ---------------------------------------------------------------------------
// K2: BAP -> featsb in MFMA-fragment layout:
//   offset(b,m,c) = (sg*4+bt)*512 + lq2*128 + bl*8 + j  (shorts)
//   sg=m*64+(c>>5), bt=b>>4, bl=b&15, lq2=(c>>3)&3, j=c&7.
// grid(32,16), block 256: each block owns 64 c x 4 CONSECUTIVE b (a full
// bl-quad), computes bap with MFMA per b, transposes through a 16KB LDS
// tile, and stores 4 contiguous dwordx4 per thread = full 64B lines
// (x1 write amplification, was x4 with per-b scalar stores).
// ---------------------------------------------------------------------------
__global__ __launch_bounds__(256) void k2_bap(
    const float* __restrict__ x, const short* __restrict__ Apad,
    short* __restrict__ featsb) {
  __shared__ short tb[8192];   // [m][och][lq2][bi][j] = m*256+och*128+lq2*32+bi*8+j
  const int t = threadIdx.x;
  const int w = t >> 6, lane = t & 63, lq = lane >> 4, ln = lane & 15;
  const int cx = blockIdx.x;           // c-tile 0..31
  const int bq = blockIdx.y;           // b-quad 0..15
  const int cl = w * 16 + ln;          // c within tile 0..63
  const int c = cx * 64 + cl;
  const float sc = 1.f / (float)HW_N;
  const int och = cl >> 5, lq2w = (cl >> 3) & 3, j = cl & 7;

#pragma unroll
  for (int bi = 0; bi < 4; ++bi) {
    const int b = bq * 4 + bi;
    const float* __restrict__ xrow = x + (size_t)b * (C_N * HW_N) + (size_t)c * HW_N;
    const short* __restrict__ ap0 = Apad + ((size_t)b * M_N + ln) * HWP + lq * 8;
    const short* __restrict__ ap1 = ap0 + 16 * HWP;

    f32x4 d0 = {0.f, 0.f, 0.f, 0.f}, d1 = {0.f, 0.f, 0.f, 0.f};
#pragma unroll
    for (int s = 0; s < 7; ++s) {
      bf16x8 a0 = *(const bf16x8*)(ap0 + s * 32);
      bf16x8 a1 = *(const bf16x8*)(ap1 + s * 32);
      bf16x8 bfr;
      const int h = s * 32 + lq * 8;
      if (s < 6) {
        float4 b0 = *(const float4*)(xrow + h);
        float4 b1 = *(const float4*)(xrow + h + 4);
        bfr[0]=f2bf(b0.x); bfr[1]=f2bf(b0.y); bfr[2]=f2bf(b0.z); bfr[3]=f2bf(b0.w);
        bfr[4]=f2bf(b1.x); bfr[5]=f2bf(b1.y); bfr[6]=f2bf(b1.z); bfr[7]=f2bf(b1.w);
      } else {
        // hw 192..223: only quad 0 j0..3 (hw 192..195) exists; rest hit A=0 pad
        float4 b0 = make_float4(0.f, 0.f, 0.f, 0.f);
        if (lq == 0) b0 = *(const float4*)(xrow + h);
        bfr[0]=f2bf(b0.x); bfr[1]=f2bf(b0.y); bfr[2]=f2bf(b0.z); bfr[3]=f2bf(b0.w);
        bfr[4]=0; bfr[5]=0; bfr[6]=0; bfr[7]=0;
      }
      d0 = __builtin_amdgcn_mfma_f32_16x16x32_bf16(a0, bfr, d0, 0, 0, 0);
      d1 = __builtin_amdgcn_mfma_f32_16x16x32_bf16(a1, bfr, d1, 0, 0, 0);
    }
    // deposit into transpose tile (C-layout: row m = quad*4 + reg, col = ln)
#pragma unroll
    for (int r = 0; r < 4; ++r) {
      int m0 = lq * 4 + r;
      tb[m0 * 256 + och * 128 + lq2w * 32 + bi * 8 + j]        = f2bf(d0[r] * sc);
      tb[(16 + m0) * 256 + och * 128 + lq2w * 32 + bi * 8 + j] = f2bf(d1[r] * sc);
    }
  }
  __syncthreads();

  // epilogue: thread t owns 32 consecutive shorts (m, och, lq2) x (bi,j)
  const int me = t >> 3, oche = (t >> 2) & 1, lq2e = t & 3;
  const short* srcp = tb + t * 32;
  uint4 v0 = *(const uint4*)(srcp);
  uint4 v1 = *(const uint4*)(srcp + 8);
  uint4 v2 = *(const uint4*)(srcp + 16);
  uint4 v3 = *(const uint4*)(srcp + 24);
  const int sg = me * 64 + cx * 2 + oche;
  const int bt = bq >> 2;
  short* dst = featsb + (size_t)(sg * 4 + bt) * 512 + lq2e * 128 + (bq & 3) * 32;
  *(uint4*)(dst)      = v0;
  *(uint4*)(dst + 8)  = v1;
  *(uint4*)(dst + 16) = v2;
  *(uint4*)(dst + 24) = v3;
}

// ---------------------------------------------------------------------------
// K3: partial[kc][b][n] = sum_{k in chunk} feats[b][k] * Wc[n][k]
// grid(7,64), block 256, k-chunk 1024 (32 MFMA steps). No LDS, no barriers.
// A-frags: coalesced 1KB wave loads from fragment-layout featsb.
// B-frags: direct Wc float4 pairs (16 rows x 64B contiguous per lq-row).
// 1-deep software prefetch keeps ~12 loads/wave in flight.
// ---------------------------------------------------------------------------
__global__ __launch_bounds__(256) void k3_cls(
    const short* __restrict__ featsb, const float* __restrict__ Wc,
    float* __restrict__ partial) {
  const int t = threadIdx.x;
  const int w = t >> 6, lane = t & 63, lq = lane >> 4, ln = lane & 15;
  const int n = blockIdx.x * 64 + w * 16 + ln;
  const int nc = n < NC_N ? n : NC_N - 1;
  const int kc = blockIdx.y;
  const size_t k0 = (size_t)kc * 1024;
  const float* __restrict__ wrow = Wc + (size_t)nc * K_N + k0 + lq * 8;
  // fragment base: steps sg = kc*32 + s; per-step stride 2048 shorts.
  const short* __restrict__ fb = featsb + (size_t)(kc * 32) * 2048 + lane * 8;

  f32x4 acc0 = {0.f,0.f,0.f,0.f}, acc1 = {0.f,0.f,0.f,0.f};
  f32x4 acc2 = {0.f,0.f,0.f,0.f}, acc3 = {0.f,0.f,0.f,0.f};

  float4 cw0 = *(const float4*)(wrow);
  float4 cw1 = *(const float4*)(wrow + 4);
  bf16x8 ca0 = *(const bf16x8*)(fb);
  bf16x8 ca1 = *(const bf16x8*)(fb + 512);
  bf16x8 ca2 = *(const bf16x8*)(fb + 1024);
  bf16x8 ca3 = *(const bf16x8*)(fb + 1536);

#pragma unroll
  for (int s = 0; s < 32; ++s) {
    float4 nw0, nw1; bf16x8 na0, na1, na2, na3;
    if (s < 31) {                    // prefetch step s+1 before MFMAs of s
      const float* wn = wrow + (s + 1) * 32;
      nw0 = *(const float4*)(wn);
      nw1 = *(const float4*)(wn + 4);
      const short* fs = fb + (size_t)(s + 1) * 2048;
      na0 = *(const bf16x8*)(fs);
      na1 = *(const bf16x8*)(fs + 512);
      na2 = *(const bf16x8*)(fs + 1024);
      na3 = *(const bf16x8*)(fs + 1536);
    }
    bf16x8 bfr;
    bfr[0]=f2bf(cw0.x); bfr[1]=f2bf(cw0.y); bfr[2]=f2bf(cw0.z); bfr[3]=f2bf(cw0.w);
    bfr[4]=f2bf(cw1.x); bfr[5]=f2bf(cw1.y); bfr[6]=f2bf(cw1.z); bfr[7]=f2bf(cw1.w);
    acc0 = __builtin_amdgcn_mfma_f32_16x16x32_bf16(ca0, bfr, acc0, 0, 0, 0);
    acc1 = __builtin_amdgcn_mfma_f32_16x16x32_bf16(ca1, bfr, acc1, 0, 0, 0);
    acc2 = __builtin_amdgcn_mfma_f32_16x16x32_bf16(ca2, bfr, acc2, 0, 0, 0);
    acc3 = __builtin_amdgcn_mfma_f32_16x16x32_bf16(ca3, bfr, acc3, 0, 0, 0);
    if (s < 31) {
      cw0 = nw0; cw1 = nw1;
      ca0 = na0; ca1 = na1; ca2 = na2; ca3 = na3;
    }
  }
  if (n < NC_N) {
    float* po = partial + (size_t)kc * (B_N * NC_N) + n;
#pragma unroll
    for (int r = 0; r < 4; ++r) {
      int br = lq * 4 + r;                    // b within 16-tile
      po[(size_t)br * NC_N]        = acc0[r];
      po[(size_t)(16 + br) * NC_N] = acc1[r];
      po[(size_t)(32 + br) * NC_N] = acc2[r];
      po[(size_t)(48 + br) * NC_N] = acc3[r];
    }
  }
}

// ---------------------------------------------------------------------------
// K4: out[b][n] = bc[n] + sum_kc partial[kc][b][n]   (64 chunks)
// ---------------------------------------------------------------------------
__global__ __launch_bounds__(256) void k4_reduce(
    const float* __restrict__ partial, const float* __restrict__ bc,
    float* __restrict__ out) {
  int idx = blockIdx.x * 256 + threadIdx.x;  // 25344 total
  if (idx >= B_N * NC_N) return;
  int n = idx % NC_N;
  float s = bc[n];
#pragma unroll 8
  for (int kc = 0; kc < KCH; ++kc) s += partial[(size_t)kc * (B_N * NC_N) + idx];
  out[idx] = s;
}

// ---------------------------------------------------------------------------
extern "C" void kernel_launch(void* const* d_in, const int* in_sizes, int n_in,
                              void* d_out, int out_size, void* d_ws, size_t ws_size,
                              hipStream_t stream) {
  const float* x  = (const float*)d_in[0];
  const float* Wa = (const float*)d_in[1];
  const float* ba = (const float*)d_in[2];
  const float* Wc = (const float*)d_in[3];
  const float* bc = (const float*)d_in[4];
  float* out = (float*)d_out;

  char* wsb = (char*)d_ws;
  short* Apad    = (short*)(wsb);                // 64*32*224*2   = 0.92 MB
  short* featsb  = (short*)(wsb + (1u  << 20));  // 2048*2048*2   = 8.39 MB (frag layout)
  float* partial = (float*)(wsb + (10u << 20));  // 64*25344*4    = 6.49 MB
  // zbuf aliases partial region: 8*401408*4 = 12.85 MB; consumed by k1b
  // before k3 writes partial over it.
  float* zbuf    = (float*)(wsb + (10u << 20));
  (void)ws_size; (void)in_sizes; (void)n_in; (void)out_size;

  hipLaunchKernelGGL(k1a_partial, dim3(NCH, B_N), dim3(256), 0, stream,
                     x, Wa, zbuf);
  hipLaunchKernelGGL(k1b_sig, dim3(1792), dim3(256), 0, stream,
                     zbuf, ba, Apad);
  hipLaunchKernelGGL(k2_bap, dim3(32, 16), dim3(256), 0, stream,
                     x, Apad, featsb);
  hipLaunchKernelGGL(k3_cls, dim3(7, KCH), dim3(256), 0, stream,
                     featsb, Wc, partial);
  hipLaunchKernelGGL(k4_reduce, dim3(99), dim3(256), 0, stream,
                     partial, bc, out);
}